// Round 22
// baseline (913.167 us; speedup 1.0000x reference)
//
#include <hip/hip_runtime.h>
#include <hip/hip_bf16.h>

// Problem constants
#define CIN_   26
#define HIN_   721
#define WIN_   1440
#define K_     9
#define HOUT_  360
#define KH_    9
#define KW_    9
#define COUT_  256
#define WOUT_  720

#define WT     16                 // w-tile width (720/16 = 45 tiles per h)
#define XSP    48                 // xs row pitch in u16 (96 B)
#define CCH    7                  // c-chunk (4 rounds: 7,7,7,5); chunk rows = 63
#define CK     (CIN_ * K_)        // 234
#define NKS2   9                  // phase-2 k-steps (k' = c*10+m, padded 288)
#define ACCP2  296                // u16 pitch: 592 B rows (16B aligned)
#define NMT    (COUT_ / 16)       // 16 m-tiles
#define NXCD   8
#define TW     5                  // tiles per block (45 = 9 groups * 5)

typedef short bf16x8 __attribute__((ext_vector_type(8)));
typedef float f32x4  __attribute__((ext_vector_type(4)));

// Fragment-ordered bf16 weight in k'-layout: [(mt*NKS2+ks)*64 + lane]*8 + j  (144 KB)
__device__ unsigned short g_whi[NMT * NKS2 * 64 * 8];
// Per-h psi A-fragments for phase 1: [(h*3 + ks)*64 + lane]*8 + e  (1.1 MB)
__device__ unsigned short g_pfrag[HOUT_ * 3 * 64 * 8];

__device__ __forceinline__ unsigned short f2bf_rne(float f) {
    union { float f; unsigned u; } v; v.f = f;
    unsigned u = v.u;
    unsigned r = (u + 0x7FFFu + ((u >> 16) & 1u)) >> 16;
    return (unsigned short)r;
}
__device__ __forceinline__ unsigned pack_bf2(float a, float b) {
    const __hip_bfloat162 bv = __float22bfloat162_rn(make_float2(a, b));
    return *reinterpret_cast<const unsigned*>(&bv);
}

// A-operand layout for mfma_f32_16x16x32_bf16: row m = lane&15, k = ks*32 + (lane>>4)*8 + j
// k' decoding: c = k'/10, m = k'%10; m==9 or k'>=260 -> zero
__global__ void prep_weight_kernel(const float* __restrict__ weight) {
    const int bid  = blockIdx.x;        // 0..143  (mt*NKS2 + ks)
    const int mt   = bid / NKS2;
    const int ks   = bid % NKS2;
    const int lane = threadIdx.x;       // 0..63
    const int row  = mt * 16 + (lane & 15);
    const int k0   = ks * 32 + (lane >> 4) * 8;
    const int base = ((mt * NKS2 + ks) * 64 + lane) * 8;
    #pragma unroll
    for (int j = 0; j < 8; ++j) {
        const int kp = k0 + j;
        float w = 0.f;
        if (kp < 260) {
            const int c = kp / 10, m = kp % 10;
            if (m < 9) w = weight[row * CK + c * 9 + m];
        }
        g_whi[base + j] = f2bf_rne(w);
    }
}

// Phase-1 contraction ordering over the 81 (dh,dw) taps, padded to 96:
//   slot s in [0,72):  dh = s>>3, dw = s&7    (adjacent-dw pairs)
//   slot s in [72,81): dh = s-72, dw = 8      (the dw=8 singles)
//   slot s in [81,96): zero padding
__global__ void prep_psi_kernel(const float* __restrict__ psi) {
    const int h    = blockIdx.x;        // 0..359
    const int lane = threadIdx.x;       // 0..63
    const int m    = lane & 15;
    const int kg   = lane >> 4;
    #pragma unroll
    for (int ks = 0; ks < 3; ++ks) {
        const int base = ((h * 3 + ks) * 64 + lane) * 8;
        #pragma unroll
        for (int e = 0; e < 8; ++e) {
            const int s = ks * 32 + kg * 8 + e;
            float v = 0.f;
            if (m < 9) {
                if (s < 72)      v = psi[(m * HOUT_ + h) * 81 + (s >> 3) * 9 + (s & 7)];
                else if (s < 81) v = psi[(m * HOUT_ + h) * 81 + (s - 72) * 9 + 8];
            }
            g_pfrag[base + e] = f2bf_rne(v);
        }
    }
}

// barrier that does NOT drain vmcnt: flush own LDS writes, then raw s_barrier
#define LDS_BARRIER()                                      \
    do {                                                   \
        asm volatile("s_waitcnt lgkmcnt(0)" ::: "memory"); \
        __builtin_amdgcn_s_barrier();                      \
    } while (0)

__global__ __launch_bounds__(512, 4)
void disco_fused_kernel(const float* __restrict__ x,
                        const int*   __restrict__ hi_base,
                        float* __restrict__ out)
{
    __shared__ unsigned short xs_bf[2][CCH * KH_][XSP];           // 2*63*48*2 = 12096 B
    __shared__ __align__(16) unsigned short acc_s[2][WT][ACCP2];  // 2*16*296*2 = 18944 B
                                                                  // total 31040 -> 2 blocks/CU (wave-capped)

    // grid 3240 = 8 XCDs * 405; per XCD: 405 = 45 h * 9 groups of 5 tiles
    const int b     = blockIdx.x;
    const int xcd   = b & (NXCD - 1);
    const int g     = b >> 3;           // 0..404
    const int h     = xcd * 45 + g / 9;
    const int tile0 = (g % 9) * TW;     // base tile in this h
    const int tid   = threadIdx.x;

    const int hib = hi_base[h];         // in [0, 716]
    const bool producer = (tid < 256);

    // ---- zero both acc buffers' k'-padding cols [260,288) ----
    if (tid < 2 * 16 * 14) {
        const int p  = tid / 224;
        const int r2 = tid % 224;
        *reinterpret_cast<unsigned*>(&acc_s[p][r2 / 14][260 + 2 * (r2 % 14)]) = 0u;
    }

    const int lane = tid & 63;
    const int widp = tid >> 6;          // 0..7
    const int n    = lane & 15;
    const int kg   = lane >> 4;

    // ---- producer: psi A-fragments (per h, once per block) ----
    bf16x8 afrag[3];
    if (producer) {
        #pragma unroll
        for (int ks = 0; ks < 3; ++ks)
            afrag[ks] = *(const bf16x8*)&g_pfrag[((h * 3 + ks) * 64 + lane) * 8];
    }

    // consumer wave index and weight base
    const int wid2 = widp - 4;          // 0..3 for consumers
    const unsigned short* wp = g_whi +
        ((size_t)(((widp & 3) * 4)) * NKS2 * 64 + lane) * 8;

    // staging macros (producer waves only; tid in 0..255)
    #define ISSUE(RD, C0V, V, S)                                                     \
    do {                                                                             \
        const int items = ((RD) == 3) ? 450 : 630;                                   \
        _Pragma("unroll")                                                            \
        for (int t_ = 0; t_ < 3; ++t_) {                                             \
            const int i  = tid + t_ * 256;                                           \
            const int ii = (i < items) ? i : (items - 1);                            \
            const int q  = ii % 10;                                                  \
            const int lr = ii / 10;                                                  \
            const int dh = lr % 9;                                                   \
            const int c  = (RD) * CCH + lr / 9;                                      \
            int r = hib + dh;                                                        \
            if (r > HIN_ - 1) r = HIN_ - 1;                                          \
            int gg = (C0V) + 4 * q;                                                  \
            if (gg < 0)          gg += WIN_;                                         \
            else if (gg >= WIN_) gg -= WIN_;                                         \
            V[t_] = *reinterpret_cast<const float4*>(                                \
                x + ((size_t)c * HIN_ + r) * WIN_ + gg);                             \
            S[t_] = (i < items) ? (lr * XSP + 4 * q) : -1;                           \
        }                                                                            \
    } while (0)

    #define WRITE(RD, V, S)                                                          \
    do {                                                                             \
        unsigned short* dst = &xs_bf[(RD) & 1][0][0];                                \
        _Pragma("unroll")                                                            \
        for (int t_ = 0; t_ < 3; ++t_) {                                             \
            if (S[t_] >= 0) {                                                        \
                uint2 dv;                                                            \
                dv.x = pack_bf2(V[t_].x, V[t_].y);                                   \
                dv.y = pack_bf2(V[t_].z, V[t_].w);                                   \
                *reinterpret_cast<uint2*>(dst + S[t_]) = dv;                         \
            }                                                                        \
        }                                                                            \
    } while (0)

    float4 va[3], vb[3];
    int    sa[3], sb[3];

    f32x4 C0 = {0.f, 0.f, 0.f, 0.f}, C1 = C0, C2 = C0, C3 = C0;
    bf16x8 wc[4];

    for (int t = 0; t <= TW; ++t) {
        const bool prod_act = producer && (t < TW);
        const bool cons_act = (!producer) && (t > 0);
        const int  c0p = 2 * ((tile0 + t) * WT) - 4;      // producer tile cols
        const int  qb  = (t - 1) & 1;                     // consumer acc buffer

        // ---- prologue slot: producer fills xs buf0, issues chunk1;
        //      consumer zeroes C and loads ks=0 weight fragments ----
        if (prod_act) {
            ISSUE(0, c0p, va, sa);
            WRITE(0, va, sa);
            ISSUE(1, c0p, vb, sb);
        }
        if (cons_act) {
            C0 = (f32x4){0.f, 0.f, 0.f, 0.f}; C1 = C0; C2 = C0; C3 = C0;
            #pragma unroll
            for (int i = 0; i < 4; ++i)
                wc[i] = *(const bf16x8*)(wp + (size_t)i * NKS2 * 512);
        }
        LDS_BARRIER();

        #pragma unroll
        for (int rd = 0; rd < 4; ++rd) {
            if (prod_act) {
                const int nc = (rd == 3) ? (CIN_ - 3 * CCH) : CCH;   // 7,7,7,5
                const char* xsb = (const char*)&xs_bf[rd & 1][0][0];
                for (int cc = widp; cc < nc; cc += 4) {
                    const int c    = rd * CCH + cc;
                    const int base = cc * (KH_ * XSP * 2) + 4 * n;
                    f32x4 Cp = {0.f, 0.f, 0.f, 0.f};
                    #pragma unroll
                    for (int ks = 0; ks < 3; ++ks) {
                        union { bf16x8 v; unsigned d[4]; unsigned short u[8]; } bf;
                        if (ks < 2 || kg == 0) {
                            const char* p = xsb + base + (ks * 4 + kg) * (XSP * 2);
                            #pragma unroll
                            for (int t_ = 0; t_ < 4; ++t_)
                                bf.d[t_] = *(const unsigned*)(p + 4 * t_);
                        } else if (kg == 1) {
                            #pragma unroll
                            for (int e = 0; e < 8; ++e)
                                bf.u[e] = *(const unsigned short*)(xsb + base + e * (XSP * 2) + 16);
                        } else if (kg == 2) {
                            bf.d[0] = bf.d[1] = bf.d[2] = bf.d[3] = 0;
                            bf.u[0] = *(const unsigned short*)(xsb + base + 8 * (XSP * 2) + 16);
                        } else {
                            bf.d[0] = bf.d[1] = bf.d[2] = bf.d[3] = 0;
                        }
                        Cp = __builtin_amdgcn_mfma_f32_16x16x32_bf16(afrag[ks], bf.v, Cp, 0, 0, 0);
                    }
                    if (kg < 2) {
                        unsigned* ap = reinterpret_cast<unsigned*>(&acc_s[t & 1][n][c * 10 + kg * 4]);
                        ap[0] = pack_bf2(Cp[0], Cp[1]);
                        ap[1] = pack_bf2(Cp[2], Cp[3]);
                    } else if (kg == 2) {
                        *reinterpret_cast<unsigned*>(&acc_s[t & 1][n][c * 10 + 8]) = pack_bf2(Cp[0], 0.f);
                    }
                }
                if (rd == 0)      { WRITE(1, vb, sb); ISSUE(2, c0p, va, sa); }
                else if (rd == 1) { WRITE(2, va, sa); ISSUE(3, c0p, vb, sb); }
                else if (rd == 2) { WRITE(3, vb, sb); }
            }

            if (cons_act) {
                if (rd < 3) {
                    // ks triple rd*3 .. rd*3+2
                    #pragma unroll
                    for (int kq = 0; kq < 3; ++kq) {
                        const int ks = rd * 3 + kq;
                        bf16x8 wn[4];
                        if (ks + 1 < NKS2) {
                            #pragma unroll
                            for (int i = 0; i < 4; ++i)
                                wn[i] = *(const bf16x8*)(wp + ((size_t)i * NKS2 + (ks + 1)) * 512);
                        }
                        const bf16x8 bq = *(const bf16x8*)&acc_s[qb][n][ks * 32 + kg * 8];
                        C0 = __builtin_amdgcn_mfma_f32_16x16x32_bf16(wc[0], bq, C0, 0, 0, 0);
                        C1 = __builtin_amdgcn_mfma_f32_16x16x32_bf16(wc[1], bq, C1, 0, 0, 0);
                        C2 = __builtin_amdgcn_mfma_f32_16x16x32_bf16(wc[2], bq, C2, 0, 0, 0);
                        C3 = __builtin_amdgcn_mfma_f32_16x16x32_bf16(wc[3], bq, C3, 0, 0, 0);
                        if (ks + 1 < NKS2) {
                            #pragma unroll
                            for (int i = 0; i < 4; ++i) wc[i] = wn[i];
                        }
                    }
                } else {
                    // epilogue for consumer tile t-1
                    const int w0c = (tile0 + t - 1) * WT;
                    #pragma unroll
                    for (int i = 0; i < 4; ++i) {
                        const f32x4 acc = (i == 0) ? C0 : (i == 1) ? C1 : (i == 2) ? C2 : C3;
                        const int m0 = (wid2 * 4 + i) * 16 + kg * 4;
                        #pragma unroll
                        for (int r = 0; r < 4; ++r) {
                            out[(size_t)(m0 + r) * (HOUT_ * WOUT_) + h * WOUT_ + w0c + n] = acc[r];
                        }
                    }
                }
            }
            LDS_BARRIER();
        }
    }
    #undef ISSUE
    #undef WRITE
}

extern "C" void kernel_launch(void* const* d_in, const int* in_sizes, int n_in,
                              void* d_out, int out_size, void* d_ws, size_t ws_size,
                              hipStream_t stream)
{
    const float* x       = (const float*)d_in[0];
    const float* psi     = (const float*)d_in[1];
    const float* weight  = (const float*)d_in[2];
    const int*   hi_base = (const int*)d_in[3];
    float* out = (float*)d_out;

    hipLaunchKernelGGL(prep_weight_kernel, dim3(NMT * NKS2), dim3(64), 0, stream, weight);
    hipLaunchKernelGGL(prep_psi_kernel,    dim3(HOUT_),      dim3(64), 0, stream, psi);

    dim3 grid(3240, 1, 1);   // 8 XCDs * 405 groups (5 tiles each)
    dim3 block(512, 1, 1);
    hipLaunchKernelGGL(disco_fused_kernel, grid, block, 0, stream,
                       x, hi_base, out);
}

// Round 23
// 257.062 us; speedup vs baseline: 3.5523x; 3.5523x over previous
//
#include <hip/hip_runtime.h>
#include <hip/hip_bf16.h>

// Problem constants
#define CIN_   26
#define HIN_   721
#define WIN_   1440
#define K_     9
#define HOUT_  360
#define KH_    9
#define KW_    9
#define COUT_  256
#define WOUT_  720

#define WT     16                 // w-tile per block (720/16 = 45 tiles)
#define XFP    40                 // xs row pitch in f32 (exactly 10 float4 -> DMA-linear)
#define CCH    7                  // c-chunk (4 rounds: 7,7,7,5); chunk rows = 63
#define CK     (CIN_ * K_)        // 234
#define NKS2   9                  // phase-2 k-steps (k' = c*10+m, padded 288)
#define ACCP2  296                // u16 pitch: 592 B rows (16B aligned)
#define NMT    (COUT_ / 16)       // 16 m-tiles
#define NXCD   8
#define HBAND  (HOUT_ / NXCD)     // 45 h-rows per XCD band

typedef short bf16x8 __attribute__((ext_vector_type(8)));
typedef float f32x4  __attribute__((ext_vector_type(4)));

// Fragment-ordered bf16 weight in k'-layout: [(mt*NKS2+ks)*64 + lane]*8 + j  (144 KB)
__device__ unsigned short g_whi[NMT * NKS2 * 64 * 8];
// Per-h psi A-fragments for phase 1: [(h*3 + ks)*64 + lane]*8 + e  (1.1 MB)
__device__ unsigned short g_pfrag[HOUT_ * 3 * 64 * 8];

__device__ __forceinline__ unsigned short f2bf_rne(float f) {
    union { float f; unsigned u; } v; v.f = f;
    unsigned u = v.u;
    unsigned r = (u + 0x7FFFu + ((u >> 16) & 1u)) >> 16;
    return (unsigned short)r;
}
__device__ __forceinline__ unsigned pack_bf2(float a, float b) {
    const __hip_bfloat162 bv = __float22bfloat162_rn(make_float2(a, b));
    return *reinterpret_cast<const unsigned*>(&bv);
}
// async global->LDS DMA, 16B per lane; LDS dest = uniform base + lane*16
__device__ __forceinline__ void gload_lds16(const float* g, float* l) {
    __builtin_amdgcn_global_load_lds(
        (const __attribute__((address_space(1))) void*)g,
        (__attribute__((address_space(3))) void*)l,
        16, 0, 0);
}

// A-operand layout for mfma_f32_16x16x32_bf16: row m = lane&15, k = ks*32 + (lane>>4)*8 + j
// k' decoding: c = k'/10, m = k'%10; m==9 or k'>=260 -> zero
__global__ void prep_weight_kernel(const float* __restrict__ weight) {
    const int bid  = blockIdx.x;        // 0..143  (mt*NKS2 + ks)
    const int mt   = bid / NKS2;
    const int ks   = bid % NKS2;
    const int lane = threadIdx.x;       // 0..63
    const int row  = mt * 16 + (lane & 15);
    const int k0   = ks * 32 + (lane >> 4) * 8;
    const int base = ((mt * NKS2 + ks) * 64 + lane) * 8;
    #pragma unroll
    for (int j = 0; j < 8; ++j) {
        const int kp = k0 + j;
        float w = 0.f;
        if (kp < 260) {
            const int c = kp / 10, m = kp % 10;
            if (m < 9) w = weight[row * CK + c * 9 + m];
        }
        g_whi[base + j] = f2bf_rne(w);
    }
}

// Phase-1 contraction ordering over the 81 (dh,dw) taps, padded to 96:
//   slot s in [0,72):  dh = s>>3, dw = s&7    (adjacent-dw pairs)
//   slot s in [72,81): dh = s-72, dw = 8      (the dw=8 singles)
//   slot s in [81,96): zero padding
__global__ void prep_psi_kernel(const float* __restrict__ psi) {
    const int h    = blockIdx.x;        // 0..359
    const int lane = threadIdx.x;       // 0..63
    const int m    = lane & 15;
    const int kg   = lane >> 4;
    #pragma unroll
    for (int ks = 0; ks < 3; ++ks) {
        const int base = ((h * 3 + ks) * 64 + lane) * 8;
        #pragma unroll
        for (int e = 0; e < 8; ++e) {
            const int s = ks * 32 + kg * 8 + e;
            float v = 0.f;
            if (m < 9) {
                if (s < 72)      v = psi[(m * HOUT_ + h) * 81 + (s >> 3) * 9 + (s & 7)];
                else if (s < 81) v = psi[(m * HOUT_ + h) * 81 + (s - 72) * 9 + 8];
            }
            g_pfrag[base + e] = f2bf_rne(v);
        }
    }
}

// barrier that does NOT drain vmcnt: flush own LDS writes, then raw s_barrier
#define LDS_BARRIER()                                      \
    do {                                                   \
        asm volatile("s_waitcnt lgkmcnt(0)" ::: "memory"); \
        __builtin_amdgcn_s_barrier();                      \
    } while (0)
#define VM_WAIT(N) asm volatile("s_waitcnt vmcnt(" #N ")" ::: "memory")

__global__ __launch_bounds__(256, 4)
void disco_fused_kernel(const float* __restrict__ x,
                        const int*   __restrict__ hi_base,
                        float* __restrict__ out)
{
    // f32 staging, DMA-linear: item ii -> floats [ii*4, ii*4+4); 12 groups of 64
    __shared__ float xs_f[2][12 * 256];                        // 2*12288 B = 24576 B
    __shared__ __align__(16) unsigned short acc_s[WT][ACCP2];  // 9472 B  (34048 -> 4 blocks/CU)

    const int b    = blockIdx.x;        // 0..16199
    const int xcd  = b & (NXCD - 1);
    const int jb   = b >> 3;            // 0..2024
    const int h    = xcd * HBAND + jb / 45;
    const int tile = jb % 45;
    const int w0   = tile * WT;
    const int tid  = threadIdx.x;

    const int hib = hi_base[h];         // in [0, 716]

    // ---- zero acc_s k'-padding cols [260,288) ----
    #pragma unroll
    for (int t = 0; t < 2; ++t) {
        const int e = tid + t * 256;    // 0..511
        if (e < 16 * 28) acc_s[e / 28][260 + e % 28] = 0;
    }

    const int lane = tid & 63;
    const int wid  = tid >> 6;          // 4 waves
    const int n    = lane & 15;
    const int kg   = lane >> 4;

    // ---- load psi A-fragments, then drain vmcnt so it counts ONLY DMA ----
    bf16x8 afrag[3];
    #pragma unroll
    for (int ks = 0; ks < 3; ++ks)
        afrag[ks] = *(const bf16x8*)&g_pfrag[((h * 3 + ks) * 64 + lane) * 8];
    VM_WAIT(0);

    const int c0 = 2 * w0 - 4;          // in [-4, 1404], divisible by 4

    // chunk rd: rows = nc*9 (63 or 45), items = rows*10, padded to 768 (12 groups).
    // wave wid issues groups {wid, wid+4, wid+8} -> exactly 3 DMA loads per wave.
    #define ISSUE_DMA(RD, BUF, RMAX)                                             \
    do {                                                                         \
        const int cb = (RD) * CCH;                                               \
        _Pragma("unroll")                                                        \
        for (int it = 0; it < 3; ++it) {                                         \
            const int g64 = wid + 4 * it;                                        \
            const int ii  = g64 * 64 + lane;                                     \
            int row = ii / 10;                                                   \
            const int q = ii - row * 10;                                         \
            if (row > (RMAX)) row = (RMAX);                                      \
            const int dh = row % 9;                                              \
            const int c  = cb + row / 9;                                         \
            int r = hib + dh;                                                    \
            if (r > HIN_ - 1) r = HIN_ - 1;                                      \
            int gc = c0 + 4 * q;                                                 \
            if (gc < 0)          gc += WIN_;                                     \
            else if (gc >= WIN_) gc -= WIN_;                                     \
            gload_lds16(x + ((size_t)c * HIN_ + r) * WIN_ + gc,                  \
                        &xs_f[BUF][g64 * 256]);                                  \
        }                                                                        \
    } while (0)

    // prologue: chunk0 + chunk1 in flight; wait chunk0 (own 3 newest still fly)
    ISSUE_DMA(0, 0, 62);
    ISSUE_DMA(1, 1, 62);
    VM_WAIT(3);
    LDS_BARRIER();

    // ---- 4 rounds: phase-1 on buf[rd&1]; next-next chunk DMA issued after readers done ----
    #pragma unroll
    for (int rd = 0; rd < 4; ++rd) {
        const int nc = (rd == 3) ? (CIN_ - 3 * CCH) : CCH;   // 7,7,7,5
        const float* xsf = &xs_f[rd & 1][0];

        for (int cc = wid; cc < nc; cc += 4) {
            const int c = rd * CCH + cc;
            const float* rbase = xsf + (cc * 9) * XFP + 2 * n;
            f32x4 C = {0.f, 0.f, 0.f, 0.f};
            #pragma unroll
            for (int ks = 0; ks < 3; ++ks) {
                union { bf16x8 v; unsigned d[4]; unsigned short u[8]; } bf;
                if (ks < 2 || kg == 0) {
                    // pairs: dh = ks*4 + kg (uniform per 16-lane group)
                    const float* rp = rbase + (ks * 4 + kg) * XFP;
                    #pragma unroll
                    for (int t = 0; t < 4; ++t) {
                        const float2 v2 = *reinterpret_cast<const float2*>(rp + 2 * t);
                        bf.d[t] = pack_bf2(v2.x, v2.y);
                    }
                } else if (kg == 1) {
                    // singles s=72..79: dh = e, dw = 8
                    #pragma unroll
                    for (int e = 0; e < 8; ++e)
                        bf.u[e] = f2bf_rne(rbase[e * XFP + 8]);
                } else if (kg == 2) {
                    bf.d[0] = bf.d[1] = bf.d[2] = bf.d[3] = 0;
                    bf.u[0] = f2bf_rne(rbase[8 * XFP + 8]);   // s=80
                } else {
                    bf.d[0] = bf.d[1] = bf.d[2] = bf.d[3] = 0;
                }
                C = __builtin_amdgcn_mfma_f32_16x16x32_bf16(afrag[ks], bf.v, C, 0, 0, 0);
            }
            // C row m = kg*4 + r -> acc_s[n][c*10 + m], packed pair stores (4B aligned)
            if (kg < 2) {
                unsigned* ap = reinterpret_cast<unsigned*>(&acc_s[n][c * 10 + kg * 4]);
                ap[0] = pack_bf2(C[0], C[1]);
                ap[1] = pack_bf2(C[2], C[3]);
            } else if (kg == 2) {
                *reinterpret_cast<unsigned*>(&acc_s[n][c * 10 + 8]) = pack_bf2(C[0], 0.f);
            }
        }

        if (rd == 0) {
            LDS_BARRIER();              // all waves done reading buf0
            ISSUE_DMA(2, 0, 62);        // chunk2 -> buf0
            VM_WAIT(3);                 // own chunk1 landed (chunk2 still flying)
            LDS_BARRIER();              // everyone's chunk1 landed
        } else if (rd == 1) {
            LDS_BARRIER();
            ISSUE_DMA(3, 1, 44);        // chunk3 -> buf1 (5 c's -> clamp row 44)
            VM_WAIT(3);                 // chunk2 landed
            LDS_BARRIER();
        } else if (rd == 2) {
            LDS_BARRIER();
            VM_WAIT(0);                 // chunk3 landed
            LDS_BARRIER();
        }
    }
    #undef ISSUE_DMA
    LDS_BARRIER();                      // acc_s complete before phase-2

    // ---- phase 2: C[256x16] = W[256xK'] * acc[K'x16], weight software-pipelined ----
    f32x4 C0 = {0.f, 0.f, 0.f, 0.f};
    f32x4 C1 = C0, C2 = C0, C3 = C0;

    // frag(i, ks) at wp + (i*NKS2 + ks)*512   (u16 units; 512 = 64 lanes * 8)
    const unsigned short* wp = g_whi + ((size_t)(wid * 4) * NKS2 * 64 + lane) * 8;

    bf16x8 wc[4];
    #pragma unroll
    for (int i = 0; i < 4; ++i)
        wc[i] = *(const bf16x8*)(wp + (size_t)i * NKS2 * 512);

    #pragma unroll
    for (int ks = 0; ks < NKS2; ++ks) {
        bf16x8 wn[4];
        if (ks + 1 < NKS2) {
            #pragma unroll
            for (int i = 0; i < 4; ++i)
                wn[i] = *(const bf16x8*)(wp + ((size_t)i * NKS2 + (ks + 1)) * 512);
        }
        const bf16x8 bhi = *(const bf16x8*)&acc_s[n][ks * 32 + kg * 8];
        C0 = __builtin_amdgcn_mfma_f32_16x16x32_bf16(wc[0], bhi, C0, 0, 0, 0);
        C1 = __builtin_amdgcn_mfma_f32_16x16x32_bf16(wc[1], bhi, C1, 0, 0, 0);
        C2 = __builtin_amdgcn_mfma_f32_16x16x32_bf16(wc[2], bhi, C2, 0, 0, 0);
        C3 = __builtin_amdgcn_mfma_f32_16x16x32_bf16(wc[3], bhi, C3, 0, 0, 0);
        if (ks + 1 < NKS2) {
            #pragma unroll
            for (int i = 0; i < 4; ++i) wc[i] = wn[i];
        }
    }

    // ---- epilogue: D layout col = lane&15, row = (lane>>4)*4 + reg ----
    #pragma unroll
    for (int i = 0; i < 4; ++i) {
        const f32x4 acc = (i == 0) ? C0 : (i == 1) ? C1 : (i == 2) ? C2 : C3;
        const int m0 = (wid * 4 + i) * 16 + kg * 4;
        #pragma unroll
        for (int r = 0; r < 4; ++r) {
            out[(size_t)(m0 + r) * (HOUT_ * WOUT_) + h * WOUT_ + w0 + n] = acc[r];
        }
    }
}

extern "C" void kernel_launch(void* const* d_in, const int* in_sizes, int n_in,
                              void* d_out, int out_size, void* d_ws, size_t ws_size,
                              hipStream_t stream)
{
    const float* x       = (const float*)d_in[0];
    const float* psi     = (const float*)d_in[1];
    const float* weight  = (const float*)d_in[2];
    const int*   hi_base = (const int*)d_in[3];
    float* out = (float*)d_out;

    hipLaunchKernelGGL(prep_weight_kernel, dim3(NMT * NKS2), dim3(64), 0, stream, weight);
    hipLaunchKernelGGL(prep_psi_kernel,    dim3(HOUT_),      dim3(64), 0, stream, psi);

    dim3 grid(45 * HOUT_, 1, 1);   // 16200, 1-D for XCD swizzle
    dim3 block(256, 1, 1);
    hipLaunchKernelGGL(disco_fused_kernel, grid, block, 0, stream,
                       x, hi_base, out);
}